// Round 1
// baseline (1107.545 us; speedup 1.0000x reference)
//
#include <hip/hip_runtime.h>
#include <math.h>

#define W 1024
#define H 1024
#define HW (1024*1024)
#define NP 24                 // B*C = 8*3 planes

#define VTX 64
#define VTY 32
#define VROWS 200             // 32 + 168 - 1 rounded up; covers max read row 198

#define HTX 64
#define HTY 32
#define HSTR 233              // odd stride -> conflict-free; >= max col read 230+1

// ---------- helpers ----------

__device__ __forceinline__ unsigned fenc(float f) {
  unsigned u = __float_as_uint(f);
  return (u & 0x80000000u) ? ~u : (u | 0x80000000u);
}
__device__ __forceinline__ float fdec(unsigned e) {
  unsigned u = (e & 0x80000000u) ? (e & 0x7fffffffu) : ~e;
  return __uint_as_float(u);
}

// acc[r] += sum_k w[k] * vals[idx0 + (k+r)*stride], r = 0..7
// NTAPP must be a multiple of 8 (weights zero-padded); rotation indices static after unroll.
template<int NTAPP>
__device__ __forceinline__ void conv8(const float* __restrict__ vals, const int stride,
                                      const int idx0, const float* __restrict__ w,
                                      float acc[8]) {
  float v[8];
  #pragma unroll
  for (int j = 0; j < 7; ++j) v[j] = vals[idx0 + j * stride];
  #pragma unroll 8
  for (int k = 0; k < NTAPP; ++k) {
    v[(k + 7) & 7] = vals[idx0 + (k + 7) * stride];
    const float wk = w[k];
    #pragma unroll
    for (int r = 0; r < 8; ++r) acc[r] = fmaf(wk, v[(k + r) & 7], acc[r]);
  }
}

__device__ __forceinline__ void minmax_reduce(float lmn, float lmx, unsigned* mm, float* red) {
  #pragma unroll
  for (int off = 32; off > 0; off >>= 1) {
    lmn = fminf(lmn, __shfl_xor(lmn, off));
    lmx = fmaxf(lmx, __shfl_xor(lmx, off));
  }
  const int tid = threadIdx.x;
  const int wid = tid >> 6;
  if ((tid & 63) == 0) { red[wid] = lmn; red[4 + wid] = lmx; }
  __syncthreads();
  if (tid == 0) {
    float mn = fminf(fminf(red[0], red[1]), fminf(red[2], red[3]));
    float mx = fmaxf(fmaxf(red[4], red[5]), fmaxf(red[6], red[7]));
    atomicMin(mm, fenc(mn));
    atomicMax(mm + 1, fenc(mx));
  }
}

// ---------- init: gaussian weights (packed: w15@0, w40@31, w80@112) + minmax slots ----------

__global__ void msr_init(float* __restrict__ wbuf, unsigned* __restrict__ mm) {
  __shared__ float g[176];
  __shared__ float invs;
  const int tid = threadIdx.x;
  if (tid == 0) { mm[0] = 0xFFFFFFFFu; mm[1] = 0u; }
  const int ks[3]   = {31, 81, 161};
  const float sg[3] = {15.f, 40.f, 80.f};
  const int off[3]  = {0, 31, 112};
  for (int s = 0; s < 3; ++s) {
    const int k = ks[s];
    const float sigma = sg[s];
    __syncthreads();
    if (tid < k) {
      float x = (float)tid - (float)(k - 1) * 0.5f;
      g[tid] = expf(-(x * x) / (2.f * sigma * sigma));
    }
    __syncthreads();
    if (tid == 0) {
      float ssum = 0.f;
      for (int i = 0; i < k; ++i) ssum += g[i];
      invs = 1.f / ssum;
    }
    __syncthreads();
    if (tid < k) wbuf[off[s] + tid] = g[tid] * invs;
  }
}

// padded LDS weight copy: wl[0..31]=w15p, wl[32..119]=w40p, wl[120..287]=w80p
__device__ __forceinline__ void copy_w_padded(const float* __restrict__ wbuf, float* wl) {
  const int tid = threadIdx.x;
  for (int i = tid; i < 288; i += 256) {
    float v = 0.f;
    if (i < 31) v = wbuf[i];
    else if (i >= 32 && i < 113) v = wbuf[31 + (i - 32)];
    else if (i >= 120 && i < 281) v = wbuf[112 + (i - 120)];
    wl[i] = v;
  }
}

// ---------- vertical blur, all 3 sigmas fused ----------

__global__ __launch_bounds__(256) void msr_vblur3(
    const float* __restrict__ src, float* __restrict__ d15, float* __restrict__ d40,
    float* __restrict__ d80, const float* __restrict__ wbuf) {
  __shared__ float vals[VROWS * VTX];
  __shared__ float wl[288];
  const int tid = threadIdx.x;
  const int plane = blockIdx.z;
  const int y0 = blockIdx.y * VTY;
  const int x0 = blockIdx.x * VTX;
  const float* sp = src + (size_t)plane * HW;
  for (int i = tid; i < VROWS * VTX; i += 256) {
    int row = i >> 6, col = i & 63;
    int gy = y0 - 80 + row;
    gy = gy < 0 ? -gy : (gy >= H ? 2 * H - 2 - gy : gy);
    vals[i] = sp[gy * W + x0 + col];
  }
  copy_w_padded(wbuf, wl);
  __syncthreads();
  const int tx = tid & 63, tyg = tid >> 6;
  const int rbase = tyg * 8;
  float a15[8], a40[8], a80[8];
  #pragma unroll
  for (int r = 0; r < 8; ++r) { a15[r] = 0.f; a40[r] = 0.f; a80[r] = 0.f; }
  conv8<168>(vals, VTX, (rbase + 0)  * VTX + tx, wl + 120, a80);
  conv8<88> (vals, VTX, (rbase + 40) * VTX + tx, wl + 32,  a40);
  conv8<32> (vals, VTX, (rbase + 65) * VTX + tx, wl + 0,   a15);
  const size_t obase = (size_t)plane * HW + (size_t)(y0 + rbase) * W + x0 + tx;
  #pragma unroll
  for (int r = 0; r < 8; ++r) {
    d15[obase + (size_t)r * W] = a15[r];
    d40[obase + (size_t)r * W] = a40[r];
    d80[obase + (size_t)r * W] = a80[r];
  }
}

// ---------- vertical blur, single sigma (fallback path) ----------

template<int PAD>
__global__ __launch_bounds__(256) void msr_vblur1(
    const float* __restrict__ src, float* __restrict__ dst, const float* __restrict__ wbuf) {
  constexpr int NTAP  = 2 * PAD + 1;
  constexpr int NTAPP = (NTAP + 7) & ~7;
  constexpr int ROWS  = VTY + NTAPP;      // reads go to VTY-8 + NTAPP + 6 = VTY+NTAPP-2
  constexpr int WOFF  = (PAD == 15) ? 0 : (PAD == 40 ? 31 : 112);
  __shared__ float vals[ROWS * VTX];
  __shared__ float wl[NTAPP];
  const int tid = threadIdx.x;
  const int plane = blockIdx.z;
  const int y0 = blockIdx.y * VTY;
  const int x0 = blockIdx.x * VTX;
  const float* sp = src + (size_t)plane * HW;
  for (int i = tid; i < ROWS * VTX; i += 256) {
    int row = i >> 6, col = i & 63;
    int gy = y0 - PAD + row;
    gy = gy < 0 ? -gy : (gy >= H ? 2 * H - 2 - gy : gy);
    vals[i] = sp[gy * W + x0 + col];
  }
  for (int i = tid; i < NTAPP; i += 256) wl[i] = (i < NTAP) ? wbuf[WOFF + i] : 0.f;
  __syncthreads();
  const int tx = tid & 63, tyg = tid >> 6;
  const int rbase = tyg * 8;
  float acc[8];
  #pragma unroll
  for (int r = 0; r < 8; ++r) acc[r] = 0.f;
  conv8<NTAPP>(vals, VTX, rbase * VTX + tx, wl, acc);
  const size_t obase = (size_t)plane * HW + (size_t)(y0 + rbase) * W + x0 + tx;
  #pragma unroll
  for (int r = 0; r < 8; ++r) dst[obase + (size_t)r * W] = acc[r];
}

// ---------- horizontal pass helper ----------

template<int PAD>
__device__ __forceinline__ void hpass(const float* __restrict__ src, const float* __restrict__ wl_s,
                                      float* vals, int plane, int y0, int x0,
                                      int ty, int txg, float h[8]) {
  constexpr int NTAP  = 2 * PAD + 1;
  constexpr int NTAPP = (NTAP + 7) & ~7;
  constexpr int LWE   = HTX + NTAPP - 1;   // staged cols; covers max read col
  constexpr int CB    = 80 - PAD;          // tile col base (tile col c <-> gx = x0-80+c)
  const int tid = threadIdx.x;
  const float* sp = src + (size_t)plane * HW + (size_t)y0 * W;
  __syncthreads();  // protect vals & wl from previous use
  for (int i = tid; i < HTY * LWE; i += 256) {
    int row = i / LWE, col = i - row * LWE;
    int gx = x0 - PAD + col;
    gx = gx < 0 ? -gx : (gx >= W ? 2 * W - 2 - gx : gx);
    vals[row * HSTR + CB + col] = sp[row * W + gx];
  }
  __syncthreads();
  float acc[8];
  #pragma unroll
  for (int r = 0; r < 8; ++r) acc[r] = 0.f;
  conv8<NTAPP>(vals, 1, ty * HSTR + CB + txg * 8, wl_s, acc);
  #pragma unroll
  for (int r = 0; r < 8; ++r) h[r] = acc[r];
}

// ---------- horizontal blur all 3 sigmas + log-combine + minmax ----------

__global__ __launch_bounds__(256) void msr_hblur3(
    const float* __restrict__ s15, const float* __restrict__ s40, const float* __restrict__ s80,
    const float* __restrict__ img, float* __restrict__ out,
    const float* __restrict__ wbuf, unsigned* __restrict__ mm) {
  __shared__ float vals[HTY * HSTR];
  __shared__ float wl[288];
  __shared__ float red[8];
  const int tid = threadIdx.x;
  const int plane = blockIdx.z;
  const int y0 = blockIdx.y * HTY;
  const int x0 = blockIdx.x * HTX;
  copy_w_padded(wbuf, wl);
  const int txg = tid & 7, ty = tid >> 3;
  float h80[8], h40[8], h15[8];
  hpass<80>(s80, wl + 120, vals, plane, y0, x0, ty, txg, h80);
  hpass<40>(s40, wl + 32,  vals, plane, y0, x0, ty, txg, h40);
  hpass<15>(s15, wl + 0,   vals, plane, y0, x0, ty, txg, h15);
  const size_t base = (size_t)plane * HW + (size_t)(y0 + ty) * W + x0 + txg * 8;
  const float4 i0 = *(const float4*)(img + base);
  const float4 i1 = *(const float4*)(img + base + 4);
  float xin[8] = {i0.x, i0.y, i0.z, i0.w, i1.x, i1.y, i1.z, i1.w};
  float accL[8];
  float lmn = 3.4e38f, lmx = -3.4e38f;
  #pragma unroll
  for (int r = 0; r < 8; ++r) {
    float a = 3.f * __logf(xin[r] + 1e-6f)
            - __logf(h15[r] + 2e-6f) - __logf(h40[r] + 2e-6f) - __logf(h80[r] + 2e-6f);
    accL[r] = a;
    lmn = fminf(lmn, a);
    lmx = fmaxf(lmx, a);
  }
  float4 o0 = {accL[0], accL[1], accL[2], accL[3]};
  float4 o1 = {accL[4], accL[5], accL[6], accL[7]};
  *(float4*)(out + base) = o0;
  *(float4*)(out + base + 4) = o1;
  minmax_reduce(lmn, lmx, mm, red);
}

// ---------- horizontal blur single sigma + accumulate (fallback path) ----------

template<int PAD, int MODE>   // MODE: 0=first (init from img), 1=mid, 2=last (minmax)
__global__ __launch_bounds__(256) void msr_hblur1(
    const float* __restrict__ vsrc, const float* __restrict__ img, float* __restrict__ out,
    const float* __restrict__ wbuf, unsigned* __restrict__ mm) {
  constexpr int NTAP  = 2 * PAD + 1;
  constexpr int NTAPP = (NTAP + 7) & ~7;
  constexpr int WOFF  = (PAD == 15) ? 0 : (PAD == 40 ? 31 : 112);
  __shared__ float vals[HTY * HSTR];
  __shared__ float wl[NTAPP];
  __shared__ float red[8];
  const int tid = threadIdx.x;
  const int plane = blockIdx.z;
  const int y0 = blockIdx.y * HTY;
  const int x0 = blockIdx.x * HTX;
  for (int i = tid; i < NTAPP; i += 256) wl[i] = (i < NTAP) ? wbuf[WOFF + i] : 0.f;
  const int txg = tid & 7, ty = tid >> 3;
  float h[8];
  hpass<PAD>(vsrc, wl, vals, plane, y0, x0, ty, txg, h);
  const size_t base = (size_t)plane * HW + (size_t)(y0 + ty) * W + x0 + txg * 8;
  float accL[8];
  if (MODE == 0) {
    const float4 i0 = *(const float4*)(img + base);
    const float4 i1 = *(const float4*)(img + base + 4);
    float xin[8] = {i0.x, i0.y, i0.z, i0.w, i1.x, i1.y, i1.z, i1.w};
    #pragma unroll
    for (int r = 0; r < 8; ++r) accL[r] = 3.f * __logf(xin[r] + 1e-6f) - __logf(h[r] + 2e-6f);
  } else {
    const float4 p0 = *(const float4*)(out + base);
    const float4 p1 = *(const float4*)(out + base + 4);
    float prev[8] = {p0.x, p0.y, p0.z, p0.w, p1.x, p1.y, p1.z, p1.w};
    #pragma unroll
    for (int r = 0; r < 8; ++r) accL[r] = prev[r] - __logf(h[r] + 2e-6f);
  }
  float4 o0 = {accL[0], accL[1], accL[2], accL[3]};
  float4 o1 = {accL[4], accL[5], accL[6], accL[7]};
  *(float4*)(out + base) = o0;
  *(float4*)(out + base + 4) = o1;
  if (MODE == 2) {
    float lmn = 3.4e38f, lmx = -3.4e38f;
    #pragma unroll
    for (int r = 0; r < 8; ++r) { lmn = fminf(lmn, accL[r]); lmx = fmaxf(lmx, accL[r]); }
    minmax_reduce(lmn, lmx, mm, red);
  }
}

// ---------- normalize ----------

__global__ __launch_bounds__(256) void msr_norm(float* __restrict__ out,
                                                const unsigned* __restrict__ mm) {
  const size_t i = ((size_t)blockIdx.x * 256 + threadIdx.x) * 4;
  const float mn = fdec(mm[0]);
  const float mx = fdec(mm[1]);
  const float sc = 255.f / (mx - mn);
  float4 v = *(float4*)(out + i);
  v.x = (v.x - mn) * sc;
  v.y = (v.y - mn) * sc;
  v.z = (v.z - mn) * sc;
  v.w = (v.w - mn) * sc;
  *(float4*)(out + i) = v;
}

// ---------- launch ----------

extern "C" void kernel_launch(void* const* d_in, const int* in_sizes, int n_in,
                              void* d_out, int out_size, void* d_ws, size_t ws_size,
                              hipStream_t stream) {
  const float* img = (const float*)d_in[0];
  float* out = (float*)d_out;
  float* wsf = (float*)d_ws;
  unsigned* mm = (unsigned*)d_ws;       // 2 uints
  float* wbuf = wsf + 16;               // 273 packed weights
  float* planes = wsf + 320;            // plane buffers start (1280 B, 256B-aligned)
  const size_t PLANE = (size_t)NP * HW;

  msr_init<<<1, 256, 0, stream>>>(wbuf, mm);

  dim3 blk(256);
  dim3 gv(W / VTX, H / VTY, NP);
  dim3 gh(W / HTX, H / HTY, NP);
  const bool fused = ws_size >= (320 + 3 * PLANE) * sizeof(float);
  if (fused) {
    msr_vblur3<<<gv, blk, 0, stream>>>(img, planes, planes + PLANE, planes + 2 * PLANE, wbuf);
    msr_hblur3<<<gh, blk, 0, stream>>>(planes, planes + PLANE, planes + 2 * PLANE,
                                       img, out, wbuf, mm);
  } else {
    msr_vblur1<15><<<gv, blk, 0, stream>>>(img, planes, wbuf);
    msr_hblur1<15, 0><<<gh, blk, 0, stream>>>(planes, img, out, wbuf, mm);
    msr_vblur1<40><<<gv, blk, 0, stream>>>(img, planes, wbuf);
    msr_hblur1<40, 1><<<gh, blk, 0, stream>>>(planes, img, out, wbuf, mm);
    msr_vblur1<80><<<gv, blk, 0, stream>>>(img, planes, wbuf);
    msr_hblur1<80, 2><<<gh, blk, 0, stream>>>(planes, img, out, wbuf, mm);
  }
  msr_norm<<<(unsigned)(PLANE / 1024), blk, 0, stream>>>(out, mm);
}

// Round 2
// 741.881 us; speedup vs baseline: 1.4929x; 1.4929x over previous
//
#include <hip/hip_runtime.h>
#include <math.h>
#include <string.h>

#define W 1024
#define H 1024
#define HW (1024*1024)
#define NP 24                 // B*C = 8*3 planes

// Padded tap counts (multiples of 12 for the float4-window hconv; reused by vconv).
// PE = effective left extent (window start offset), chosen ≡0 mod 4 for alignment.
#define NT80 168
#define NT40 96
#define NT15 36
#define PE80 80
#define PE40 40
#define PE15 16
#define W80OFF 0
#define W40OFF NT80
#define W15OFF (NT80 + NT40)
#define NWTOT (NT80 + NT40 + NT15)   // 300 floats = 1200 B kernarg

struct Weights { float w[NWTOT]; };

// ---------- min/max encode helpers ----------

__device__ __forceinline__ unsigned fenc(float f) {
  unsigned u = __float_as_uint(f);
  return (u & 0x80000000u) ? ~u : (u | 0x80000000u);
}
__device__ __forceinline__ float fdec(unsigned e) {
  unsigned u = (e & 0x80000000u) ? (e & 0x7fffffffu) : ~e;
  return __uint_as_float(u);
}

__device__ __forceinline__ void minmax_reduce(float lmn, float lmx, unsigned* mm, float* red) {
  #pragma unroll
  for (int off = 32; off > 0; off >>= 1) {
    lmn = fminf(lmn, __shfl_xor(lmn, off));
    lmx = fmaxf(lmx, __shfl_xor(lmx, off));
  }
  const int tid = threadIdx.x;
  const int wid = tid >> 6;
  if ((tid & 63) == 0) { red[wid] = lmn; red[4 + wid] = lmx; }
  __syncthreads();
  if (tid == 0) {
    float mn = fminf(fminf(red[0], red[1]), fminf(red[2], red[3]));
    float mx = fmaxf(fmaxf(red[4], red[5]), fmaxf(red[6], red[7]));
    atomicMin(mm, fenc(mn));
    atomicMax(mm + 1, fenc(mx));
  }
}

__global__ void msr_mm_init(unsigned* __restrict__ mm) {
  if (threadIdx.x == 0) { mm[0] = 0xFFFFFFFFu; mm[1] = 0u; }
}

// ---------- vertical blur (all 3 sigmas), thread = 2 cols x 8 rows ----------

#define VCOLS 64
#define VROWS_OUT 64
#define VSTAGE 231            // staged rows: gy in [y0-80, y0+150]

// acc2[r] += sum_k w[WOFF+k] * v2[base + k*32], sliding 8-row float2 window
template<int WOFF, int NTAPP>
__device__ __forceinline__ void vconv(const float2* __restrict__ vp, const Weights& wt,
                                      float2 acc[8]) {
  float2 v[8];
  #pragma unroll
  for (int j = 0; j < 7; ++j) v[j] = vp[j * 32];
  #pragma unroll
  for (int k = 0; k < NTAPP; ++k) {
    v[(k + 7) & 7] = vp[(k + 7) * 32];
    const float wk = wt.w[WOFF + k];
    #pragma unroll
    for (int r = 0; r < 8; ++r) {
      acc[r].x = fmaf(wk, v[(k + r) & 7].x, acc[r].x);
      acc[r].y = fmaf(wk, v[(k + r) & 7].y, acc[r].y);
    }
  }
}

__global__ __launch_bounds__(256) void msr_vblur3(
    const float* __restrict__ src, float* __restrict__ d15, float* __restrict__ d40,
    float* __restrict__ d80, Weights wt) {
  __shared__ float vals[VSTAGE * VCOLS];   // 59.1 KB
  const int tid = threadIdx.x;
  const int plane = blockIdx.z;
  const int y0 = blockIdx.y * VROWS_OUT;
  const int x0 = blockIdx.x * VCOLS;
  const float* sp = src + (size_t)plane * HW;
  // stage: float4 chunks, reflect in y only (x always in-range, aligned)
  {
    const int q = tid & 15;          // col chunk: c = 4q
    const int r0 = tid >> 4;         // 16 rows per sweep
    #pragma unroll
    for (int s = 0; s < 15; ++s) {
      int lr = r0 + 16 * s;
      if (lr < VSTAGE) {
        int gy = y0 - 80 + lr;
        gy = gy < 0 ? -gy : (gy >= H ? 2 * H - 2 - gy : gy);
        float4 t = *(const float4*)(sp + (size_t)gy * W + x0 + 4 * q);
        *(float4*)(vals + lr * VCOLS + 4 * q) = t;
      }
    }
  }
  __syncthreads();
  const int cp = tid & 31;          // column pair
  const int rbase = (tid >> 5) * 8; // row group base
  const float2* vbase = (const float2*)vals;
  const size_t obase = (size_t)plane * HW + (size_t)(y0 + rbase) * W + x0 + 2 * cp;

  float2 acc[8];
  #pragma unroll
  for (int r = 0; r < 8; ++r) acc[r] = make_float2(0.f, 0.f);
  vconv<W80OFF, NT80>(vbase + (rbase + 80 - PE80) * 32 + cp, wt, acc);
  #pragma unroll
  for (int r = 0; r < 8; ++r) *(float2*)(d80 + obase + (size_t)r * W) = acc[r];

  #pragma unroll
  for (int r = 0; r < 8; ++r) acc[r] = make_float2(0.f, 0.f);
  vconv<W40OFF, NT40>(vbase + (rbase + 80 - PE40) * 32 + cp, wt, acc);
  #pragma unroll
  for (int r = 0; r < 8; ++r) *(float2*)(d40 + obase + (size_t)r * W) = acc[r];

  #pragma unroll
  for (int r = 0; r < 8; ++r) acc[r] = make_float2(0.f, 0.f);
  vconv<W15OFF, NT15>(vbase + (rbase + 80 - PE15) * 32 + cp, wt, acc);
  #pragma unroll
  for (int r = 0; r < 8; ++r) *(float2*)(d15 + obase + (size_t)r * W) = acc[r];
}

// ---------- horizontal blur (all 3 sigmas) + log combine + minmax ----------

#define HSTR 236              // dwords per staged row; mult of 4, mod 32 = 12
#define HROWS 32

// 4 taps at weight base; window chunks c0=v[k0..k0+3], c1=+4, c2=+8
template<int K0>
__device__ __forceinline__ void tap4(const float4& c0, const float4& c1, const float4& c2,
                                     const Weights& wt, float acc[8]) {
  const float v[12] = {c0.x, c0.y, c0.z, c0.w, c1.x, c1.y, c1.z, c1.w,
                       c2.x, c2.y, c2.z, c2.w};
  #pragma unroll
  for (int t = 0; t < 4; ++t) {
    const float wk = wt.w[K0 + t];
    #pragma unroll
    for (int r = 0; r < 8; ++r) acc[r] = fmaf(wk, v[t + r], acc[r]);
  }
}

template<int WOFF, int NTAPP>
__device__ __forceinline__ void hconv(const float* __restrict__ vp, const Weights& wt,
                                      float acc[8]) {
  constexpr int NG = NTAPP / 12;
  float4 a = *(const float4*)(vp);
  float4 b = *(const float4*)(vp + 4);
  float4 c = *(const float4*)(vp + 8);
  #pragma unroll
  for (int g = 0; g < NG; ++g) {
    tap4<WOFF + 12 * 0>(a, b, c, wt, acc);  // placeholder; real K0 below via g
    // NOTE: the line above is replaced by the macro-expansion pattern below.
    a = b; // never reached; see real implementation
  }
}

// The template above can't take runtime g into K0; use explicit recursion instead.
template<int WOFF, int NTAPP, int G>
struct HGroup {
  static __device__ __forceinline__ void run(const float* __restrict__ vp, const Weights& wt,
                                             float acc[8], float4& a, float4& b, float4& c) {
    constexpr int g = NTAPP / 12 - G;
    tap4<WOFF + 12 * g + 0>(a, b, c, wt, acc);
    a = *(const float4*)(vp + 12 * g + 12);
    tap4<WOFF + 12 * g + 4>(b, c, a, wt, acc);
    b = *(const float4*)(vp + 12 * g + 16);
    tap4<WOFF + 12 * g + 8>(c, a, b, wt, acc);
    if (G > 1) c = *(const float4*)(vp + 12 * g + 20);
    HGroup<WOFF, NTAPP, G - 1>::run(vp, wt, acc, a, b, c);
  }
};
template<int WOFF, int NTAPP>
struct HGroup<WOFF, NTAPP, 0> {
  static __device__ __forceinline__ void run(const float*, const Weights&, float[8],
                                             float4&, float4&, float4&) {}
};

template<int WOFF, int NTAPP>
__device__ __forceinline__ void hconv_run(const float* __restrict__ vp, const Weights& wt,
                                          float acc[8]) {
  float4 a = *(const float4*)(vp);
  float4 b = *(const float4*)(vp + 4);
  float4 c = *(const float4*)(vp + 8);
  HGroup<WOFF, NTAPP, NTAPP / 12>::run(vp, wt, acc, a, b, c);
}

template<int NTAPP, int PE, bool FAST>
__device__ __forceinline__ void hstage(const float* __restrict__ sp /* plane+y0 row base */,
                                       float* vals, int x0, int row, int txg) {
  constexpr int LWE = 56 + NTAPP + 8;
  const float* srow = sp + (size_t)row * W;
  float* vrow = vals + row * HSTR;
  if (FAST) {
    #pragma unroll
    for (int j = 0; j < (LWE + 31) / 32; ++j) {
      int c = 4 * (txg + 8 * j);
      if (c < LWE) *(float4*)(vrow + c) = *(const float4*)(srow + x0 - PE + c);
    }
  } else {
    for (int c = txg; c < LWE; c += 8) {
      int gx = x0 - PE + c;
      gx = gx < 0 ? -gx : (gx >= W ? 2 * W - 2 - gx : gx);
      vrow[c] = srow[gx];
    }
  }
}

template<bool FAST>
__device__ __forceinline__ void hblur_body(
    const float* __restrict__ s15, const float* __restrict__ s40, const float* __restrict__ s80,
    const float* __restrict__ img, float* __restrict__ out, const Weights& wt,
    unsigned* __restrict__ mm, float* vals, float* red) {
  const int tid = threadIdx.x;
  const int plane = blockIdx.z;
  const int y0 = blockIdx.y * HROWS;
  const int x0 = blockIdx.x * 64;
  const int ty = tid >> 3, txg = tid & 7;
  const size_t pbase = (size_t)plane * HW + (size_t)y0 * W;
  const size_t obase = pbase + (size_t)ty * W + x0 + txg * 8;
  const float* vp = vals + ty * HSTR + txg * 8;

  float accL[8];
  {
    const float4 i0 = *(const float4*)(img + obase);
    const float4 i1 = *(const float4*)(img + obase + 4);
    const float xin[8] = {i0.x, i0.y, i0.z, i0.w, i1.x, i1.y, i1.z, i1.w};
    #pragma unroll
    for (int r = 0; r < 8; ++r) accL[r] = 3.f * __logf(xin[r] + 1e-6f);
  }

  float h[8];
  // pass sigma=80
  hstage<NT80, PE80, FAST>(s80 + pbase, vals, x0, ty, txg);
  __syncthreads();
  #pragma unroll
  for (int r = 0; r < 8; ++r) h[r] = 0.f;
  hconv_run<W80OFF, NT80>(vp, wt, h);
  #pragma unroll
  for (int r = 0; r < 8; ++r) accL[r] -= __logf(h[r] + 2e-6f);
  __syncthreads();
  // pass sigma=40
  hstage<NT40, PE40, FAST>(s40 + pbase, vals, x0, ty, txg);
  __syncthreads();
  #pragma unroll
  for (int r = 0; r < 8; ++r) h[r] = 0.f;
  hconv_run<W40OFF, NT40>(vp, wt, h);
  #pragma unroll
  for (int r = 0; r < 8; ++r) accL[r] -= __logf(h[r] + 2e-6f);
  __syncthreads();
  // pass sigma=15
  hstage<NT15, PE15, FAST>(s15 + pbase, vals, x0, ty, txg);
  __syncthreads();
  #pragma unroll
  for (int r = 0; r < 8; ++r) h[r] = 0.f;
  hconv_run<W15OFF, NT15>(vp, wt, h);
  #pragma unroll
  for (int r = 0; r < 8; ++r) accL[r] -= __logf(h[r] + 2e-6f);

  float lmn = 3.4e38f, lmx = -3.4e38f;
  #pragma unroll
  for (int r = 0; r < 8; ++r) { lmn = fminf(lmn, accL[r]); lmx = fmaxf(lmx, accL[r]); }
  float4 o0 = {accL[0], accL[1], accL[2], accL[3]};
  float4 o1 = {accL[4], accL[5], accL[6], accL[7]};
  *(float4*)(out + obase) = o0;
  *(float4*)(out + obase + 4) = o1;
  minmax_reduce(lmn, lmx, mm, red);
}

__global__ __launch_bounds__(256) void msr_hblur3(
    const float* __restrict__ s15, const float* __restrict__ s40, const float* __restrict__ s80,
    const float* __restrict__ img, float* __restrict__ out, Weights wt,
    unsigned* __restrict__ mm) {
  __shared__ float vals[HROWS * HSTR];   // 30.2 KB
  __shared__ float red[8];
  // fast path: all three windows fully interior -> aligned float4 staging, no reflect
  if (blockIdx.x >= 2 && blockIdx.x <= 13)
    hblur_body<true>(s15, s40, s80, img, out, wt, mm, vals, red);
  else
    hblur_body<false>(s15, s40, s80, img, out, wt, mm, vals, red);
}

// ---------- normalize ----------

__global__ __launch_bounds__(256) void msr_norm(float* __restrict__ out,
                                                const unsigned* __restrict__ mm) {
  const size_t i = ((size_t)blockIdx.x * 256 + threadIdx.x) * 4;
  const float mn = fdec(mm[0]);
  const float mx = fdec(mm[1]);
  const float sc = 255.f / (mx - mn);
  float4 v = *(float4*)(out + i);
  v.x = (v.x - mn) * sc;
  v.y = (v.y - mn) * sc;
  v.z = (v.z - mn) * sc;
  v.w = (v.w - mn) * sc;
  *(float4*)(out + i) = v;
}

// ---------- host-side weight computation (mirrors reference float math) ----------

static void compute_weights(Weights* wt) {
  memset(wt, 0, sizeof(Weights));
  const int   ntap[3]  = {161, 81, 31};
  const int   pe[3]    = {PE80, PE40, PE15};
  const int   off[3]   = {W80OFF, W40OFF, W15OFF};
  const float sigma[3] = {80.f, 40.f, 15.f};
  for (int s = 0; s < 3; ++s) {
    const int k = ntap[s];
    const int pad = k / 2;
    float g[161];
    float sum = 0.f;
    for (int i = 0; i < k; ++i) {
      float x = (float)i - (float)(k - 1) * 0.5f;
      g[i] = expf(-(x * x) / (2.f * sigma[s] * sigma[s]));
      sum += g[i];
    }
    const float inv = 1.f / sum;
    const int shift = pe[s] - pad;   // window index j = i + (PE - pad)
    for (int i = 0; i < k; ++i) wt->w[off[s] + i + shift] = g[i] * inv;
  }
}

// ---------- launch ----------

extern "C" void kernel_launch(void* const* d_in, const int* in_sizes, int n_in,
                              void* d_out, int out_size, void* d_ws, size_t ws_size,
                              hipStream_t stream) {
  const float* img = (const float*)d_in[0];
  float* out = (float*)d_out;
  float* wsf = (float*)d_ws;
  unsigned* mm = (unsigned*)d_ws;       // 2 uints
  float* planes = wsf + 320;            // 1280 B offset, 16B-aligned
  const size_t PLANE = (size_t)NP * HW;

  Weights wt;
  compute_weights(&wt);

  msr_mm_init<<<1, 64, 0, stream>>>(mm);

  dim3 blk(256);
  dim3 gv(W / VCOLS, H / VROWS_OUT, NP);
  dim3 gh(W / 64, H / HROWS, NP);
  msr_vblur3<<<gv, blk, 0, stream>>>(img, planes, planes + PLANE, planes + 2 * PLANE, wt);
  msr_hblur3<<<gh, blk, 0, stream>>>(planes, planes + PLANE, planes + 2 * PLANE,
                                     img, out, wt, mm);
  msr_norm<<<(unsigned)(PLANE / 1024), blk, 0, stream>>>(out, mm);
}

// Round 3
// 337.435 us; speedup vs baseline: 3.2823x; 2.1986x over previous
//
#include <hip/hip_runtime.h>
#include <math.h>
#include <string.h>

#define W 1024
#define H 1024
#define HW (1024*1024)
#define NP 24                 // B*C planes

typedef float  f32x4  __attribute__((ext_vector_type(4)));
typedef short  bf16x8 __attribute__((ext_vector_type(8)));

#define PITCH_S 328           // shorts per staged LDS row = 656 B; 656 mod 128 = 16 -> uniform bank slots
#define STW 320               // staged window cols (px)

struct Weights { float w[273]; };   // w80[161]@0, w40[81]@161, w15[31]@242

// ---------- helpers ----------

__device__ __forceinline__ unsigned fenc(float f) {
  unsigned u = __float_as_uint(f);
  return (u & 0x80000000u) ? ~u : (u | 0x80000000u);
}
__device__ __forceinline__ float fdec(unsigned e) {
  unsigned u = (e & 0x80000000u) ? (e & 0x7fffffffu) : ~e;
  return __uint_as_float(u);
}
__device__ __forceinline__ unsigned bfbits(float f) {   // f32 -> bf16 bits, RNE
  unsigned u = __float_as_uint(f);
  return (u + 0x7fffu + ((u >> 16) & 1u)) >> 16;
}

__device__ __forceinline__ void minmax_reduce(float lmn, float lmx, unsigned* mm, float* red) {
  #pragma unroll
  for (int off = 32; off > 0; off >>= 1) {
    lmn = fminf(lmn, __shfl_xor(lmn, off));
    lmx = fmaxf(lmx, __shfl_xor(lmx, off));
  }
  const int tid = threadIdx.x;
  const int wid = tid >> 6;
  if ((tid & 63) == 0) { red[wid] = lmn; red[4 + wid] = lmx; }
  __syncthreads();
  if (tid == 0) {
    float mn = fminf(fminf(red[0], red[1]), fminf(red[2], red[3]));
    float mx = fmaxf(fmaxf(red[4], red[5]), fmaxf(red[6], red[7]));
    atomicMin(mm, fenc(mn));
    atomicMax(mm + 1, fenc(mx));
  }
}

// ---------- init: Toeplitz B-fragment table [3][6][64 lanes] x 8 bf16 ----------
// B[kk][c] for MFMA 16x16x32: lane = 16*(kk/8) + c, elem j = kk%8.
// d(s,k) = pad + (t0+2k)*16 - 256 ; value = w[d + kk - c] if in [0,2*pad] else 0.

__global__ void msr_fraginit(Weights wt, ushort* __restrict__ frag, unsigned* __restrict__ mm) {
  const int tid = threadIdx.x;
  if (tid == 0) { mm[0] = 0xFFFFFFFFu; mm[1] = 0u; }
  const int pads[3] = {80, 40, 15};
  const int woff[3] = {0, 161, 242};
  const int t0s[3]  = {11, 13, 15};
  for (int e = tid; e < 3 * 6 * 64; e += 256) {
    const int s = e / 384;
    const int rem = e - s * 384;
    const int k = rem >> 6;
    const int lane = rem & 63;
    const int pad = pads[s];
    const int d = pad + (t0s[s] + 2 * k) * 16 - 256;
    ushort* dst = frag + e * 8;
    for (int j = 0; j < 8; ++j) {
      const int kk = ((lane >> 4) << 3) + j;
      const int c  = lane & 15;
      const int idx = d + kk - c;
      float v = (idx >= 0 && idx <= 2 * pad) ? wt.w[woff[s] + idx] : 0.f;
      dst[j] = (ushort)bfbits(v);
    }
  }
}

// ---------- conv core: 8 C-tiles (16x16) per wave from staged LDS rows ----------
// A-frag: lane -> row = lane&15 (+wave row base), k = (lane>>4)*8 + j (8 consecutive bf16).

template<int NK, int C0>
__device__ __forceinline__ void conv8tiles(const short* __restrict__ lds, int rowshort,
                                           const bf16x8 fr[NK], f32x4 c[8]) {
  #pragma unroll
  for (int tx = 0; tx < 8; ++tx) {
    f32x4 acc = {0.f, 0.f, 0.f, 0.f};
    #pragma unroll
    for (int k = 0; k < NK; ++k) {
      bf16x8 a = *(const bf16x8*)(lds + rowshort + tx * 16 + C0 + 32 * k);
      acc = __builtin_amdgcn_mfma_f32_16x16x32_bf16(a, fr[k], acc, 0, 0, 0);
    }
    c[tx] = acc;
  }
}

// ---------- pass 1: horizontal blur (3 sigmas) -> transposed bf16 planes ----------
// Block: out tile 64 rows(y) x 128 cols(x). Stage img rows y0..y0+63, x in [x0-96, x0+224).

__global__ __launch_bounds__(256) void msr_hblur3(
    const float* __restrict__ img, ushort* __restrict__ planesT,
    const bf16x8* __restrict__ fragv) {
  __shared__ __align__(16) short lds[64 * PITCH_S];
  const int tid = threadIdx.x;
  // bijective XCD swizzle: consecutive x-tiles (halo-sharing) -> same XCD
  const int orig = blockIdx.x + (blockIdx.y << 3) + (blockIdx.z << 7);
  const int l = (orig & 7) * 384 + (orig >> 3);
  const int bx = l & 7;            // x-tile (128 wide)
  const int by = (l >> 3) & 15;    // y-tile (64 tall)
  const int bp = l >> 7;           // plane
  const int x0 = bx * 128, y0 = by * 64;
  const float* sp = img + (size_t)bp * HW;

  // stage 64 x 320 px as bf16
  const int row = tid >> 2;
  const bool interior = (bx >= 1 && bx <= 6);
  if (interior) {
    #pragma unroll
    for (int it = 0; it < 20; ++it) {
      const int ccpx = 4 * (tid & 3) + 16 * it;
      const float4 v = *(const float4*)(sp + (size_t)(y0 + row) * W + (x0 - 96 + ccpx));
      const unsigned lo = bfbits(v.x) | (bfbits(v.y) << 16);
      const unsigned hi = bfbits(v.z) | (bfbits(v.w) << 16);
      *(uint2*)(lds + row * PITCH_S + ccpx) = make_uint2(lo, hi);
    }
  } else {
    #pragma unroll
    for (int it = 0; it < 20; ++it) {
      const int ccpx = 4 * (tid & 3) + 16 * it;
      unsigned us[4];
      #pragma unroll
      for (int j = 0; j < 4; ++j) {
        int gx = x0 - 96 + ccpx + j;
        gx = gx < 0 ? -gx : (gx >= W ? 2 * W - 2 - gx : gx);
        us[j] = bfbits(sp[(size_t)(y0 + row) * W + gx]);
      }
      *(uint2*)(lds + row * PITCH_S + ccpx) = make_uint2(us[0] | (us[1] << 16), us[2] | (us[3] << 16));
    }
  }
  __syncthreads();

  const int lane = tid & 63;
  const int wrow = (tid >> 6) * 16;
  const int rowshort = (wrow + (lane & 15)) * PITCH_S + ((lane >> 4) << 3);
  const int xb16 = x0 + (lane & 15);
  const int yb = y0 + wrow + ((lane >> 4) << 2);

  // sigma 80 (s=0, NK=6, C0=16)
  {
    bf16x8 fr[6];
    #pragma unroll
    for (int k = 0; k < 6; ++k) fr[k] = fragv[k * 64 + lane];
    f32x4 c[8];
    conv8tiles<6, 16>(lds, rowshort, fr, c);
    ushort* pT = planesT + (size_t)(0 * NP + bp) * HW;
    #pragma unroll
    for (int tx = 0; tx < 8; ++tx) {
      const unsigned lo = bfbits(c[tx][0]) | (bfbits(c[tx][1]) << 16);
      const unsigned hi = bfbits(c[tx][2]) | (bfbits(c[tx][3]) << 16);
      *(uint2*)(pT + (size_t)(xb16 + tx * 16) * W + yb) = make_uint2(lo, hi);
    }
  }
  // sigma 40 (s=1, NK=4, C0=48)
  {
    bf16x8 fr[4];
    #pragma unroll
    for (int k = 0; k < 4; ++k) fr[k] = fragv[(6 + k) * 64 + lane];
    f32x4 c[8];
    conv8tiles<4, 48>(lds, rowshort, fr, c);
    ushort* pT = planesT + (size_t)(1 * NP + bp) * HW;
    #pragma unroll
    for (int tx = 0; tx < 8; ++tx) {
      const unsigned lo = bfbits(c[tx][0]) | (bfbits(c[tx][1]) << 16);
      const unsigned hi = bfbits(c[tx][2]) | (bfbits(c[tx][3]) << 16);
      *(uint2*)(pT + (size_t)(xb16 + tx * 16) * W + yb) = make_uint2(lo, hi);
    }
  }
  // sigma 15 (s=2, NK=2, C0=80)
  {
    bf16x8 fr[2];
    #pragma unroll
    for (int k = 0; k < 2; ++k) fr[k] = fragv[(12 + k) * 64 + lane];
    f32x4 c[8];
    conv8tiles<2, 80>(lds, rowshort, fr, c);
    ushort* pT = planesT + (size_t)(2 * NP + bp) * HW;
    #pragma unroll
    for (int tx = 0; tx < 8; ++tx) {
      const unsigned lo = bfbits(c[tx][0]) | (bfbits(c[tx][1]) << 16);
      const unsigned hi = bfbits(c[tx][2]) | (bfbits(c[tx][3]) << 16);
      *(uint2*)(pT + (size_t)(xb16 + tx * 16) * W + yb) = make_uint2(lo, hi);
    }
  }
}

// ---------- pass 2: vertical blur (3 sigmas) over planesT + log combine + minmax ----------
// Block: out tile 64(x) x 128(y). planeT row conv: rows = x, k-axis = y.

template<int S, int NK, int C0>
__device__ __forceinline__ void k2_round(const ushort* __restrict__ planesT, int bp, int x0, int y0,
                                         short* __restrict__ lds, const bf16x8* __restrict__ fragv,
                                         int tid, int lane, int rowshort, float* accL, bool interior) {
  const ushort* pTs = planesT + (size_t)(S * NP + bp) * HW;
  const int row = tid >> 2;
  if (interior) {
    #pragma unroll
    for (int it = 0; it < 10; ++it) {
      const int ccpx = 8 * (tid & 3) + 32 * it;
      *(uint4*)(lds + row * PITCH_S + ccpx) =
          *(const uint4*)(pTs + (size_t)(x0 + row) * W + (y0 - 96 + ccpx));
    }
  } else {
    #pragma unroll
    for (int it = 0; it < 10; ++it) {
      const int ccpx = 8 * (tid & 3) + 32 * it;
      #pragma unroll
      for (int j = 0; j < 8; ++j) {
        int gy = y0 - 96 + ccpx + j;
        gy = gy < 0 ? -gy : (gy >= H ? 2 * H - 2 - gy : gy);
        lds[row * PITCH_S + ccpx + j] = (short)pTs[(size_t)(x0 + row) * W + gy];
      }
    }
  }
  __syncthreads();
  bf16x8 fr[NK];
  #pragma unroll
  for (int k = 0; k < NK; ++k) fr[k] = fragv[(S * 6 + k) * 64 + lane];
  f32x4 c[8];
  conv8tiles<NK, C0>(lds, rowshort, fr, c);
  #pragma unroll
  for (int tx = 0; tx < 8; ++tx) {
    #pragma unroll
    for (int r = 0; r < 4; ++r) accL[tx * 4 + r] -= __logf(c[tx][r] + 2e-6f);
  }
  __syncthreads();
}

__global__ __launch_bounds__(256) void msr_vblur3(
    const ushort* __restrict__ planesT, const float* __restrict__ img,
    float* __restrict__ out, const bf16x8* __restrict__ fragv, unsigned* __restrict__ mm) {
  __shared__ __align__(16) short lds[64 * PITCH_S];
  __shared__ float red[8];
  const int tid = threadIdx.x;
  const int orig = blockIdx.x + (blockIdx.y << 3) + (blockIdx.z << 7);
  const int l = (orig & 7) * 384 + (orig >> 3);
  const int byt = l & 7;           // y-tile (128 tall, halo axis)
  const int bxt = (l >> 3) & 15;   // x-tile (64 wide)
  const int bp = l >> 7;
  const int x0 = bxt * 64, y0 = byt * 128;
  const int lane = tid & 63;
  const int wrow = (tid >> 6) * 16;
  const int rowshort = (wrow + (lane & 15)) * PITCH_S + ((lane >> 4) << 3);
  const int xb = x0 + wrow + ((lane >> 4) << 2);   // 4 consecutive x per lane (regs)
  const int ycb = y0 + (lane & 15);                // y per lane (+ tx*16)
  const bool interior = (byt >= 1 && byt <= 6);

  float accL[32];
  const float* ip = img + (size_t)bp * HW;
  #pragma unroll
  for (int tx = 0; tx < 8; ++tx) {
    const float4 v = *(const float4*)(ip + (size_t)(ycb + tx * 16) * W + xb);
    accL[tx * 4 + 0] = 3.f * __logf(v.x + 1e-6f);
    accL[tx * 4 + 1] = 3.f * __logf(v.y + 1e-6f);
    accL[tx * 4 + 2] = 3.f * __logf(v.z + 1e-6f);
    accL[tx * 4 + 3] = 3.f * __logf(v.w + 1e-6f);
  }

  k2_round<0, 6, 16>(planesT, bp, x0, y0, lds, fragv, tid, lane, rowshort, accL, interior);
  k2_round<1, 4, 48>(planesT, bp, x0, y0, lds, fragv, tid, lane, rowshort, accL, interior);
  k2_round<2, 2, 80>(planesT, bp, x0, y0, lds, fragv, tid, lane, rowshort, accL, interior);

  float* op = out + (size_t)bp * HW;
  float lmn = 3.4e38f, lmx = -3.4e38f;
  #pragma unroll
  for (int tx = 0; tx < 8; ++tx) {
    #pragma unroll
    for (int r = 0; r < 4; ++r) {
      lmn = fminf(lmn, accL[tx * 4 + r]);
      lmx = fmaxf(lmx, accL[tx * 4 + r]);
    }
    *(float4*)(op + (size_t)(ycb + tx * 16) * W + xb) =
        make_float4(accL[tx * 4 + 0], accL[tx * 4 + 1], accL[tx * 4 + 2], accL[tx * 4 + 3]);
  }
  minmax_reduce(lmn, lmx, mm, red);
}

// ---------- normalize ----------

__global__ __launch_bounds__(256) void msr_norm(float* __restrict__ out,
                                                const unsigned* __restrict__ mm) {
  const size_t i = ((size_t)blockIdx.x * 256 + threadIdx.x) * 4;
  const float mn = fdec(mm[0]);
  const float mx = fdec(mm[1]);
  const float sc = 255.f / (mx - mn);
  float4 v = *(float4*)(out + i);
  v.x = (v.x - mn) * sc;
  v.y = (v.y - mn) * sc;
  v.z = (v.z - mn) * sc;
  v.w = (v.w - mn) * sc;
  *(float4*)(out + i) = v;
}

// ---------- host-side weights (mirrors reference float math) ----------

static void compute_weights(Weights* wt) {
  memset(wt, 0, sizeof(Weights));
  const int   ntap[3]  = {161, 81, 31};
  const int   off[3]   = {0, 161, 242};
  const float sigma[3] = {80.f, 40.f, 15.f};
  for (int s = 0; s < 3; ++s) {
    const int k = ntap[s];
    float g[161];
    float sum = 0.f;
    for (int i = 0; i < k; ++i) {
      float x = (float)i - (float)(k - 1) * 0.5f;
      g[i] = expf(-(x * x) / (2.f * sigma[s] * sigma[s]));
      sum += g[i];
    }
    const float inv = 1.f / sum;
    for (int i = 0; i < k; ++i) wt->w[off[s] + i] = g[i] * inv;
  }
}

// ---------- launch ----------

extern "C" void kernel_launch(void* const* d_in, const int* in_sizes, int n_in,
                              void* d_out, int out_size, void* d_ws, size_t ws_size,
                              hipStream_t stream) {
  const float* img = (const float*)d_in[0];
  float* out = (float*)d_out;
  unsigned* mm = (unsigned*)d_ws;
  ushort* frag = (ushort*)((char*)d_ws + 256);
  ushort* planesT = (ushort*)((char*)d_ws + 32768);

  Weights wt;
  compute_weights(&wt);

  msr_fraginit<<<1, 256, 0, stream>>>(wt, frag, mm);
  msr_hblur3<<<dim3(8, 16, NP), 256, 0, stream>>>(img, planesT, (const bf16x8*)frag);
  msr_vblur3<<<dim3(8, 16, NP), 256, 0, stream>>>(planesT, img, out, (const bf16x8*)frag, mm);
  msr_norm<<<(unsigned)((size_t)NP * HW / 1024), 256, 0, stream>>>(out, mm);
}